// Round 3
// baseline (255.874 us; speedup 1.0000x reference)
//
#include <hip/hip_runtime.h>

// Problem constants: B=4, C=3, H=512, W=960, K2=16 -> K=4
#define BB 4
#define CC 3
#define HH 512
#define WW 960
#define HW (HH * WW)
#define NPIX (BB * HW)

// Tile geometry: 64x4 pixels per 256-thread block.
#define TLX 64
#define TLY 4
#define NTX (WW / TLX)   // 15
#define NTY (HH / TLY)   // 128
// Staged halo: rows [y0-9, y0+14] (24 rows), cols [x0-12, x0+79] (92 cols).
#define NR 24
#define RPAD 9
#define NCOL 92
#define CPAD 12

__global__ __launch_bounds__(256)
void filter_interp_tiled(const float* __restrict__ inp,
                         const float* __restrict__ flow,
                         const float* __restrict__ filt,
                         float* __restrict__ out) {
    const int lx = threadIdx.x & 63;
    const int ly = threadIdx.x >> 6;
    int blk = blockIdx.x;
    const int tx = blk % NTX; blk /= NTX;
    const int ty = blk % NTY;
    const int b  = blk / NTY;
    const int x0 = tx * TLX;
    const int y0 = ty * TLY;
    const int x  = x0 + lx;
    const int y  = y0 + ly;
    const int rem = y * WW + x;

    __shared__ __align__(16) float sm[CC * NR * NCOL];  // 26.5 KB

    // ---- Stage clamped input halo into LDS (coalesced float4) ----
    const float* ib = inp + (size_t)b * CC * HW;
    const int c0 = x0 - CPAD;   // multiple of 4 (x0 mult of 64)
    const int r0 = y0 - RPAD;
    for (int idx = threadIdx.x; idx < CC * NR * (NCOL / 4); idx += 256) {
        const int ch = idx / (NR * (NCOL / 4));
        const int rm = idx - ch * NR * (NCOL / 4);
        const int r  = rm / (NCOL / 4);
        const int m  = rm - r * (NCOL / 4);
        const int gr = min(max(r0 + r, 0), HH - 1);
        const int gcb = c0 + 4 * m;
        const float* rowp = ib + (size_t)ch * HW + (size_t)gr * WW;
        float4 v;
        if (gcb >= 0 && gcb + 3 < WW) {
            v = *(const float4*)(rowp + gcb);
        } else {
            v.x = rowp[min(max(gcb,     0), WW - 1)];
            v.y = rowp[min(max(gcb + 1, 0), WW - 1)];
            v.z = rowp[min(max(gcb + 2, 0), WW - 1)];
            v.w = rowp[min(max(gcb + 3, 0), WW - 1)];
        }
        *(float4*)(&sm[(ch * NR + r) * NCOL + 4 * m]) = v;
    }
    __syncthreads();

    // ---- Per-pixel work ----
    const float fx = flow[(b * 2 + 0) * HW + rem];
    const float fy = flow[(b * 2 + 1) * HW + rem];
    const float x2 = (float)x + fx;
    const float y2 = (float)y + fy;

    const bool valid = (x2 >= 0.0f) && (x2 <= (float)(WW - 1)) &&
                       (y2 >= 0.0f) && (y2 <= (float)(HH - 1)) &&
                       (fabsf(fx) < (float)WW * 0.5f) &&
                       (fabsf(fy) < (float)HH * 0.5f);

    float acc[3] = {0.0f, 0.0f, 0.0f};

    if (valid) {
        const int ix = (int)floorf(x2);
        const int iy = (int)floorf(y2);
        const float alpha = x2 - (float)ix;
        const float beta  = y2 - (float)iy;

        const float wTL = (1.0f - alpha) * (1.0f - beta);
        const float wTR = alpha * (1.0f - beta);
        const float wBL = (1.0f - alpha) * beta;
        const float wBR = alpha * beta;

        // Fold 16 filter taps x 4 bilinear weights into 5x5 weight map.
        float Wm[5][5];
#pragma unroll
        for (int j = 0; j < 5; ++j)
#pragma unroll
            for (int i = 0; i < 5; ++i) Wm[j][i] = 0.0f;

        const float* fptr = filt + (size_t)b * 16 * HW + rem;
#pragma unroll
        for (int dj = 0; dj < 4; ++dj) {
#pragma unroll
            for (int di = 0; di < 4; ++di) {
                const float f = fptr[(size_t)(dj * 4 + di) * HW];
                Wm[dj][di]         += f * wTL;
                Wm[dj][di + 1]     += f * wTR;
                Wm[dj + 1][di]     += f * wBL;
                Wm[dj + 1][di + 1] += f * wBR;
            }
        }

        const int ixL0 = ix - 1;
        const int iyT0 = iy - 1;
        const int k0 = iyT0 - r0;        // staged row index of patch top
        const int d  = ixL0 - c0;        // staged col of patch left
        const int a0 = d & ~3;
        const int o  = d & 3;

        const bool fast = (k0 >= 0) && (k0 <= NR - 5) &&
                          (d >= 0) && (a0 + 8 <= NCOL);

        if (fast) {
            // Barrel-shift 5-wide weight rows into 8-wide windows:
            // We[j][i] = Wm[j][i-o] (0 outside).
            const bool s2 = (o & 2) != 0;
            const bool s1 = (o & 1) != 0;
            float We[5][8];
#pragma unroll
            for (int j = 0; j < 5; ++j) {
                float t[8];
#pragma unroll
                for (int i = 0; i < 8; ++i) t[i] = (i < 5) ? Wm[j][i] : 0.0f;
                float u[8];
#pragma unroll
                for (int i = 0; i < 8; ++i)
                    u[i] = s2 ? ((i >= 2) ? t[i - 2] : 0.0f) : t[i];
#pragma unroll
                for (int i = 0; i < 8; ++i)
                    We[j][i] = s1 ? ((i >= 1) ? u[i - 1] : 0.0f) : u[i];
            }

#pragma unroll
            for (int j = 0; j < 5; ++j) {
                const int rowbase = (k0 + j) * NCOL + a0;
#pragma unroll
                for (int c = 0; c < CC; ++c) {
                    const float* sp = &sm[c * (NR * NCOL) + rowbase];
                    const float4 p0 = *(const float4*)(sp);
                    const float4 p1 = *(const float4*)(sp + 4);
                    float a = acc[c];
                    a += p0.x * We[j][0];
                    a += p0.y * We[j][1];
                    a += p0.z * We[j][2];
                    a += p0.w * We[j][3];
                    a += p1.x * We[j][4];
                    a += p1.y * We[j][5];
                    a += p1.z * We[j][6];
                    a += p1.w * We[j][7];
                    acc[c] = a;
                }
            }
        } else {
            // Rare slow path (|flow| beyond staged halo): clamped global
            // scalar gathers — identical to verified round-1 logic.
            int S[5], R[5];
#pragma unroll
            for (int i = 0; i < 5; ++i) {
                S[i] = min(max(ixL0 + i, 0), WW - 1);
                R[i] = min(max(iyT0 + i, 0), HH - 1);
            }
#pragma unroll
            for (int c = 0; c < CC; ++c) {
                const float* ic = ib + (size_t)c * HW;
                float a = 0.0f;
#pragma unroll
                for (int j = 0; j < 5; ++j) {
                    const float* row = ic + (size_t)R[j] * WW;
#pragma unroll
                    for (int i = 0; i < 5; ++i) a += row[S[i]] * Wm[j][i];
                }
                acc[c] = a;
            }
        }
    }

    const int outbase = b * CC * HW + rem;
    out[outbase]          = acc[0];
    out[outbase + HW]     = acc[1];
    out[outbase + 2 * HW] = acc[2];
}

extern "C" void kernel_launch(void* const* d_in, const int* in_sizes, int n_in,
                              void* d_out, int out_size, void* d_ws, size_t ws_size,
                              hipStream_t stream) {
    const float* teninput  = (const float*)d_in[0];
    const float* tenflow   = (const float*)d_in[1];
    const float* tenfilter = (const float*)d_in[2];
    float* out = (float*)d_out;

    const int blocks = NTX * NTY * BB;  // 7680
    filter_interp_tiled<<<blocks, 256, 0, stream>>>(teninput, tenflow, tenfilter, out);
}